// Round 20
// baseline (238.397 us; speedup 1.0000x reference)
//
#include <hip/hip_runtime.h>
#include <math.h>

#define NB 4
#define NT 2048
#define NC 1024
#define NHEADS 16
#define HDIM 64

typedef __attribute__((ext_vector_type(8))) _Float16 half8v;
typedef __attribute__((ext_vector_type(2))) __fp16 fp16x2;
typedef __attribute__((ext_vector_type(4))) float f32x4;

#define LOG2E 1.4426950408889634f

__device__ inline unsigned short f2h(float f) {
    _Float16 h = (_Float16)f;
    return __builtin_bit_cast(unsigned short, h);
}
__device__ inline float h2f(unsigned short u) {
    return (float)__builtin_bit_cast(_Float16, u);
}
__device__ inline float exp2fast(float x) {
#if __has_builtin(__builtin_amdgcn_exp2f)
    return __builtin_amdgcn_exp2f(x);
#else
    return exp2f(x);
#endif
}
__device__ inline unsigned int pack2h(float a, float b) {
    fp16x2 p = __builtin_amdgcn_cvt_pkrtz(a, b);
    return __builtin_bit_cast(unsigned int, p);
}

#define AS1C(p) ((const __attribute__((address_space(1))) unsigned int*)(unsigned long long)(const void*)(p))
#define AS3P(p) ((__attribute__((address_space(3))) unsigned int*)(unsigned int)(unsigned long long)(void*)(p))
#define GLL16(gp, lp) __builtin_amdgcn_global_load_lds(AS1C(gp), AS3P(lp), 16, 0, 0)

// ---------------------------------------------------------------------------
// fp32 -> fp16 convert (vectorized)
// ---------------------------------------------------------------------------
__global__ __launch_bounds__(256) void conv_f16_kernel(
    const float* __restrict__ in, unsigned short* __restrict__ out, int n4)
{
    const int i = blockIdx.x * 256 + threadIdx.x;
    if (i >= n4) return;
    const float4 f = ((const float4*)in)[i];
    ushort4 h;
    h.x = f2h(f.x); h.y = f2h(f.y); h.z = f2h(f.z); h.w = f2h(f.w);
    ((ushort4*)out)[i] = h;
}

// ---------------------------------------------------------------------------
// mask fp32 -> fp16 * log2e, Q-QUAD layout: mask5[b][q>>2][k][q&3] so that
// attention lane (g,fr) loads one ushort4 = {j=0..3} (4 consecutive q-rows)
// for fixed k -- maps directly onto the MFMA C fragment Sm[nt][j].
// ---------------------------------------------------------------------------
__global__ __launch_bounds__(256) void mask_conv_kernel(
    const float* __restrict__ in, unsigned short* __restrict__ out)
{
    const size_t o = (size_t)blockIdx.x * 256 + threadIdx.x;  // ushort4 index
    const int k = (int)(o & 2047);
    const int Q = (int)((o >> 11) & 511);
    const int b = (int)(o >> 20);
    const float* ip = in + (((size_t)b * 2048 + 4 * Q) * 2048 + k);
    ushort4 v;
    v.x = f2h(ip[0] * LOG2E);
    v.y = f2h(ip[2048] * LOG2E);
    v.z = f2h(ip[4096] * LOG2E);
    v.w = f2h(ip[6144] * LOG2E);
    ((ushort4*)out)[o] = v;
}

// ---------------------------------------------------------------------------
// Kernel 1: qkv = x @ w^T + b via fp16 MFMA, fused RoPE. K-loop double-
// buffered. q fp16 (B,NH,T,D) PRE-SCALED by scl*log2e; k fp16;
// v TRANSPOSED+key-PERMUTED fp16 (pi(nt*16+fr) = fr*4+nt).
// ---------------------------------------------------------------------------
__global__ __launch_bounds__(256) void qkv_gemm_kernel(
    const unsigned short* __restrict__ xf, const unsigned short* __restrict__ wf,
    const float* __restrict__ bias, const float* __restrict__ pe_cos,
    const float* __restrict__ pe_sin, const float* __restrict__ pe_scale,
    unsigned short* __restrict__ qb, unsigned short* __restrict__ kb,
    unsigned short* __restrict__ vtb)
{
    __shared__ __align__(16) unsigned short Ah[2][128 * 32];
    __shared__ __align__(16) unsigned short Bh[2][128 * 32];

    const int tid = threadIdx.x;
    const int w = tid >> 6, lane = tid & 63;
    const int g = lane >> 4, fr = lane & 15;
    const int wr = w >> 1, wc = w & 1;

    const int bid = blockIdx.x;                 // 1536 blocks, XCD swizzle
    const int s = (bid & 7) * 192 + (bid >> 3);
    const int m0 = (s & 63) * 128, n0 = (s >> 6) * 128;

    const int c0 = tid, c1 = tid + 256;
    const int r0 = c0 >> 2, r1 = c1 >> 2;
    const int cb0 = ((c0 & 3) * 16) ^ (((r0 >> 1) & 3) << 4);
    const int cb1 = ((c1 & 3) * 16) ^ (((r1 >> 1) & 3) << 4);
    const unsigned short* px0 = xf + (size_t)(m0 + r0) * NC + (cb0 >> 1);
    const unsigned short* px1 = xf + (size_t)(m0 + r1) * NC + (cb1 >> 1);
    const unsigned short* pw0 = wf + (size_t)(n0 + r0) * NC + (cb0 >> 1);
    const unsigned short* pw1 = wf + (size_t)(n0 + r1) * NC + (cb1 >> 1);

#define GSTAGE(buf, k0)                                                         \
    do {                                                                        \
        GLL16(px0 + (k0), (char*)Ah[buf] + c0 * 16);                            \
        GLL16(px1 + (k0), (char*)Ah[buf] + c1 * 16);                            \
        GLL16(pw0 + (k0), (char*)Bh[buf] + c0 * 16);                            \
        GLL16(pw1 + (k0), (char*)Bh[buf] + c1 * 16);                            \
    } while (0)

    f32x4 acc[4][4];
#pragma unroll
    for (int m = 0; m < 4; ++m)
#pragma unroll
        for (int n = 0; n < 4; ++n) acc[m][n] = (f32x4){0.f, 0.f, 0.f, 0.f};

    GSTAGE(0, 0);
    __syncthreads();
    int cur = 0;

    for (int k0 = 0; k0 < NC; k0 += 32) {
        if (k0 + 32 < NC) GSTAGE(cur ^ 1, k0 + 32);

        half8v a_f[4], b_f[4];
#pragma unroll
        for (int m = 0; m < 4; ++m) {
            const int r = wr * 64 + m * 16 + fr;
            const int off = r * 64 + ((g * 16) ^ (((r >> 1) & 3) << 4));
            a_f[m] = *(const half8v*)((const char*)Ah[cur] + off);
        }
#pragma unroll
        for (int n = 0; n < 4; ++n) {
            const int r = wc * 64 + n * 16 + fr;
            const int off = r * 64 + ((g * 16) ^ (((r >> 1) & 3) << 4));
            b_f[n] = *(const half8v*)((const char*)Bh[cur] + off);
        }
#pragma unroll
        for (int m = 0; m < 4; ++m)
#pragma unroll
            for (int n = 0; n < 4; ++n)
                acc[m][n] = __builtin_amdgcn_mfma_f32_16x16x32_f16(a_f[m], b_f[n], acc[m][n], 0, 0, 0);

        __syncthreads();   // drains vmcnt(0): next tile staged; cur reusable
        cur ^= 1;
    }

    // Epilogue: bias + RoPE (+*scale*scl*log2e q, /scale k), scatter.
    const float QSCL = 0.08838834764831845f * LOG2E;  // 1/sqrt(2*D) * log2e
#pragma unroll
    for (int n = 0; n < 4; ++n) {
        const int col = n0 + wc * 64 + n * 16 + fr;
        const int part = col >> 10;             // wave-uniform (16-col span)
        const int hh = (col & 1023) >> 6;
        const int dd = col & 63;
        const float bv = bias[col];
        if (part < 2) {
            unsigned short* outp = (part == 0) ? qb : kb;
#pragma unroll
            for (int m = 0; m < 4; ++m) {
                const int row0 = m0 + wr * 64 + m * 16 + 4 * g;
                const int bb = row0 >> 11;
                const int t0 = row0 & 2047;
#pragma unroll
                for (int j = 0; j < 4; ++j) {
                    const int t = t0 + j;
                    float val = acc[m][n][j] + bv;
                    const float partner = __shfl_xor(val, 1, 64);
                    const int pidx = t * HDIM + dd;
                    const float cc = pe_cos[pidx], ss = pe_sin[pidx], sc = pe_scale[pidx];
                    const float r = (dd & 1) ? (val * cc + partner * ss)
                                             : (val * cc - partner * ss);
                    val = (part == 0) ? (r * sc * QSCL) : (r / sc);
                    outp[(((size_t)bb * NHEADS + hh) * NT + t) * HDIM + dd] = f2h(val);
                }
            }
        } else {
            // v: key-permuted transpose. Thread holds keys {nt=m, fr'=4g+j}
            // across m -> pos (4g+j)*4 + m are 4 consecutive -> ushort4.
            const int rowb = m0 + wr * 64;       // 64-aligned
            const int bb = rowb >> 11;
            const int tb = rowb & 2047;
            unsigned short* vp2 =
                &vtb[(((size_t)bb * NHEADS + hh) * HDIM + dd) * NT + tb];
#pragma unroll
            for (int j = 0; j < 4; ++j) {
                ushort4 sv;
                sv.x = f2h(acc[0][n][j] + bv);
                sv.y = f2h(acc[1][n][j] + bv);
                sv.z = f2h(acc[2][n][j] + bv);
                sv.w = f2h(acc[3][n][j] + bv);
                *(ushort4*)&vp2[(4 * g + j) * 4] = sv;
            }
        }
    }
}

// ---------------------------------------------------------------------------
// Kernel 2: flash attention, fp16 MFMA (round-17 structure = best measured).
// Mask (fp16, q-quad, log2e-prescaled) enters as the QK^T MFMA C-init.
// kt-loop UNROLLED x2 with named mask reg buffers (deletes the 16-vmov
// copy tail) and s_setprio(1) around the PV MFMA cluster (T5).
// ---------------------------------------------------------------------------
__global__ __launch_bounds__(256) void attn_mfma_kernel(
    const unsigned short* __restrict__ qb, const unsigned short* __restrict__ kb,
    const unsigned short* __restrict__ vtb, const unsigned short* __restrict__ m16,
    float* __restrict__ out)
{
    __shared__ __align__(16) unsigned short Ks[2][64 * 64];
    __shared__ __align__(16) unsigned short Vs[2][64 * 64];
    __shared__ __align__(16) unsigned short Ps[4][32 * 64];

    const int tid = threadIdx.x;
    const int w = tid >> 6, lane = tid & 63;
    const int g = lane >> 4, fr = lane & 15;

    const int bid = blockIdx.x;                  // 1024 blocks, XCD swizzle
    const int s = (bid & 7) * 128 + (bid >> 3);
    const int q0 = (s & 15) * 128;
    const int h = (s >> 4) & 15;
    const int b = s >> 8;

    const size_t bh = (size_t)b * NHEADS + h;
    const unsigned short* qp = qb + (bh * NT + q0 + w * 32) * HDIM;
    const unsigned short* kp = kb + bh * NT * HDIM;
    const unsigned short* vtp = vtb + bh * HDIM * NT;
    // q-quad mask base: Qbase = (q0 + w*32) >> 2
    const unsigned short* mp =
        m16 + 4 * (((size_t)b * 512 + ((q0 + w * 32) >> 2)) * 2048);

    const int sc0 = tid, sc1 = tid + 256;
    const int sr0 = sc0 >> 3, scb0 = ((sc0 & 7) * 16) ^ ((sr0 & 7) << 4);
    const int sr1 = sc1 >> 3, scb1 = ((sc1 & 7) * 16) ^ ((sr1 & 7) << 4);

#define STAGE(buf, kt)                                                          \
    do {                                                                        \
        const unsigned short* ktp_ = kp + (kt) * 64 * HDIM;                     \
        GLL16(ktp_ + sr0 * HDIM + (scb0 >> 1), (char*)Ks[buf] + sc0 * 16);      \
        GLL16(vtp + (size_t)sr0 * NT + (kt) * 64 + (scb0 >> 1),                 \
              (char*)Vs[buf] + sc0 * 16);                                       \
        GLL16(ktp_ + sr1 * HDIM + (scb1 >> 1), (char*)Ks[buf] + sc1 * 16);      \
        GLL16(vtp + (size_t)sr1 * NT + (kt) * 64 + (scb1 >> 1),                 \
              (char*)Vs[buf] + sc1 * 16);                                       \
    } while (0)

// dst[m][nt] = {mask(q=4*(Qbase+m*4+g)+j, k=kt*64+nt*16+fr)} j=0..3
#define MLOAD(dst, kt)                                                          \
    do {                                                                        \
        _Pragma("unroll")                                                       \
        for (int m_ = 0; m_ < 2; ++m_) {                                        \
            _Pragma("unroll")                                                   \
            for (int nt_ = 0; nt_ < 4; ++nt_)                                   \
                dst[m_][nt_] = *(const ushort4*)(                               \
                    mp + ((m_ * 4 + g) * 2048 + (kt) * 64 + nt_ * 16 + fr) * 4); \
        }                                                                       \
    } while (0)

    half8v qf[2][2];
#pragma unroll
    for (int m = 0; m < 2; ++m)
#pragma unroll
        for (int kk = 0; kk < 2; ++kk)
            qf[m][kk] = *(const half8v*)(qp + (m * 16 + fr) * HDIM + kk * 32 + g * 8);

    f32x4 acc[2][4];
    float li[2][4];
#pragma unroll
    for (int m = 0; m < 2; ++m)
#pragma unroll
        for (int j = 0; j < 4; ++j) {
            li[m][j] = 0.f;
            acc[m][j] = (f32x4){0.f, 0.f, 0.f, 0.f};
        }

    // compute body for one K/V tile (BUF) with mask regs MV
    auto body = [&](const unsigned short* KsB, const unsigned short* VsB,
                    const ushort4 (&mv)[2][4]) {
        half8v kf[4][2];
#pragma unroll
        for (int nt = 0; nt < 4; ++nt) {
            const int r = nt * 16 + fr;
#pragma unroll
            for (int kk = 0; kk < 2; ++kk) {
                const int off = r * 128 + ((kk * 64 + g * 16) ^ ((r & 7) << 4));
                kf[nt][kk] = *(const half8v*)((const char*)KsB + off);
            }
        }

#pragma unroll
        for (int m = 0; m < 2; ++m) {
            f32x4 Sm[4];
#pragma unroll
            for (int nt = 0; nt < 4; ++nt) {
                const ushort4 mq = mv[m][nt];
                Sm[nt] = (f32x4){h2f(mq.x), h2f(mq.y), h2f(mq.z), h2f(mq.w)};
#pragma unroll
                for (int kk = 0; kk < 2; ++kk)
                    Sm[nt] = __builtin_amdgcn_mfma_f32_16x16x32_f16(qf[m][kk], kf[nt][kk], Sm[nt], 0, 0, 0);
            }
#pragma unroll
            for (int j = 0; j < 4; ++j) {
                const float p0 = exp2fast(Sm[0][j]);
                const float p1 = exp2fast(Sm[1][j]);
                const float p2 = exp2fast(Sm[2][j]);
                const float p3 = exp2fast(Sm[3][j]);
                li[m][j] += (p0 + p1) + (p2 + p3);
                uint2 pw2;
                pw2.x = pack2h(p0, p1);
                pw2.y = pack2h(p2, p3);
                const int prow = m * 16 + 4 * g + j;
                const int off = prow * 128 + ((fr * 8) ^ ((prow & 7) << 4));
                *(uint2*)((char*)Ps[w] + off) = pw2;
            }
        }

        half8v vf[4][2];
#pragma unroll
        for (int dt = 0; dt < 4; ++dt) {
            const int d = dt * 16 + fr;
#pragma unroll
            for (int kk = 0; kk < 2; ++kk) {
                const int off = d * 128 + ((kk * 64 + g * 16) ^ ((d & 7) << 4));
                vf[dt][kk] = *(const half8v*)((const char*)VsB + off);
            }
        }
        __builtin_amdgcn_s_setprio(1);
#pragma unroll
        for (int m = 0; m < 2; ++m) {
            half8v pf[2];
#pragma unroll
            for (int kk = 0; kk < 2; ++kk) {
                const int off = (m * 16 + fr) * 128 + ((kk * 64 + g * 16) ^ ((fr & 7) << 4));
                pf[kk] = *(const half8v*)((const char*)Ps[w] + off);
            }
#pragma unroll
            for (int dt = 0; dt < 4; ++dt)
#pragma unroll
                for (int kk = 0; kk < 2; ++kk)
                    acc[m][dt] = __builtin_amdgcn_mfma_f32_16x16x32_f16(pf[kk], vf[dt][kk], acc[m][dt], 0, 0, 0);
        }
        __builtin_amdgcn_s_setprio(0);
    };

    ushort4 mA[2][4], mB[2][4];
    MLOAD(mA, 0);
    STAGE(0, 0);
    __syncthreads();

    for (int kt = 0; kt < NT / 64; kt += 2) {
        // iter A: compute on buf0/mA, prefetch kt+1 into buf1/mB
        if (kt + 1 < NT / 64) {
            STAGE(1, kt + 1);
            MLOAD(mB, kt + 1);
        }
        body(Ks[0], Vs[0], mA);
        __syncthreads();

        // iter B: compute on buf1/mB, prefetch kt+2 into buf0/mA
        if (kt + 2 < NT / 64) {
            STAGE(0, kt + 2);
            MLOAD(mA, kt + 2);
        }
        body(Ks[1], Vs[1], mB);
        __syncthreads();
    }

#pragma unroll
    for (int m = 0; m < 2; ++m)
#pragma unroll
        for (int j = 0; j < 4; ++j) {
            float lt = li[m][j];
            lt += __shfl_xor(lt, 1, 64);
            lt += __shfl_xor(lt, 2, 64);
            lt += __shfl_xor(lt, 4, 64);
            lt += __shfl_xor(lt, 8, 64);
            const float inv = 1.f / lt;
            const int t = q0 + w * 32 + m * 16 + 4 * g + j;
            float* op = out + (((size_t)b * NT + t) * NHEADS + h) * HDIM;
#pragma unroll
            for (int dt = 0; dt < 4; ++dt) op[dt * 16 + fr] = acc[m][dt][j] * inv;
        }
}

extern "C" void kernel_launch(void* const* d_in, const int* in_sizes, int n_in,
                              void* d_out, int out_size, void* d_ws, size_t ws_size,
                              hipStream_t stream) {
    const float* x        = (const float*)d_in[0];
    const float* pe_cos   = (const float*)d_in[1];
    const float* pe_sin   = (const float*)d_in[2];
    const float* pe_scale = (const float*)d_in[3];
    const float* mask     = (const float*)d_in[4];
    const float* w_qkv    = (const float*)d_in[5];
    const float* b_qkv    = (const float*)d_in[6];
    float* out = (float*)d_out;

    unsigned short* ws = (unsigned short*)d_ws;
    const size_t PER = (size_t)NB * NHEADS * NT * HDIM;   // 8388608
    unsigned short* qbuf = ws;
    unsigned short* kbuf = ws + PER;
    unsigned short* vtbuf = ws + 2 * PER;
    unsigned short* xbuf = ws + 3 * PER;                  // fp16 x (GEMM only)
    unsigned short* wbuf = xbuf + (size_t)NB * NT * NC;   // fp16 w (GEMM only)
    unsigned short* maskbuf = ws + 3 * PER;               // fp16 mask (after GEMM)

    conv_f16_kernel<<<8192, 256, 0, stream>>>(x, xbuf, (NB * NT * NC) / 4);
    conv_f16_kernel<<<3072, 256, 0, stream>>>(w_qkv, wbuf, (3 * NC * NC) / 4);
    qkv_gemm_kernel<<<1536, 256, 0, stream>>>(xbuf, wbuf, b_qkv,
                                              pe_cos, pe_sin, pe_scale,
                                              qbuf, kbuf, vtbuf);
    mask_conv_kernel<<<16384, 256, 0, stream>>>(mask, maskbuf);
    attn_mfma_kernel<<<1024, 256, 0, stream>>>(qbuf, kbuf, vtbuf, maskbuf, out);
}

// Round 21
// 229.759 us; speedup vs baseline: 1.0376x; 1.0376x over previous
//
#include <hip/hip_runtime.h>
#include <math.h>

#define NB 4
#define NT 2048
#define NC 1024
#define NHEADS 16
#define HDIM 64

typedef __attribute__((ext_vector_type(8))) _Float16 half8v;
typedef __attribute__((ext_vector_type(2))) __fp16 fp16x2;
typedef __attribute__((ext_vector_type(4))) float f32x4;

#define LOG2E 1.4426950408889634f

__device__ inline unsigned short f2h(float f) {
    _Float16 h = (_Float16)f;
    return __builtin_bit_cast(unsigned short, h);
}
__device__ inline float h2f(unsigned short u) {
    return (float)__builtin_bit_cast(_Float16, u);
}
__device__ inline float exp2fast(float x) {
#if __has_builtin(__builtin_amdgcn_exp2f)
    return __builtin_amdgcn_exp2f(x);
#else
    return exp2f(x);
#endif
}
__device__ inline unsigned int pack2h(float a, float b) {
    fp16x2 p = __builtin_amdgcn_cvt_pkrtz(a, b);
    return __builtin_bit_cast(unsigned int, p);
}

#define AS1C(p) ((const __attribute__((address_space(1))) unsigned int*)(unsigned long long)(const void*)(p))
#define AS3P(p) ((__attribute__((address_space(3))) unsigned int*)(unsigned int)(unsigned long long)(void*)(p))
#define GLL16(gp, lp) __builtin_amdgcn_global_load_lds(AS1C(gp), AS3P(lp), 16, 0, 0)

// ---------------------------------------------------------------------------
// fp32 -> fp16 convert (vectorized)
// ---------------------------------------------------------------------------
__global__ __launch_bounds__(256) void conv_f16_kernel(
    const float* __restrict__ in, unsigned short* __restrict__ out, int n4)
{
    const int i = blockIdx.x * 256 + threadIdx.x;
    if (i >= n4) return;
    const float4 f = ((const float4*)in)[i];
    ushort4 h;
    h.x = f2h(f.x); h.y = f2h(f.y); h.z = f2h(f.z); h.w = f2h(f.w);
    ((ushort4*)out)[i] = h;
}

// ---------------------------------------------------------------------------
// mask fp32 -> fp16 * log2e, Q-QUAD layout: mask5[b][q>>2][k][q&3] so that
// attention lane (g,fr) loads one ushort4 = {j=0..3} (4 consecutive q-rows)
// for fixed k -- maps directly onto the MFMA C fragment Sm[nt][j].
// ---------------------------------------------------------------------------
__global__ __launch_bounds__(256) void mask_conv_kernel(
    const float* __restrict__ in, unsigned short* __restrict__ out)
{
    const size_t o = (size_t)blockIdx.x * 256 + threadIdx.x;  // ushort4 index
    const int k = (int)(o & 2047);
    const int Q = (int)((o >> 11) & 511);
    const int b = (int)(o >> 20);
    const float* ip = in + (((size_t)b * 2048 + 4 * Q) * 2048 + k);
    ushort4 v;
    v.x = f2h(ip[0] * LOG2E);
    v.y = f2h(ip[2048] * LOG2E);
    v.z = f2h(ip[4096] * LOG2E);
    v.w = f2h(ip[6144] * LOG2E);
    ((ushort4*)out)[o] = v;
}

// ---------------------------------------------------------------------------
// Kernel 1: qkv = x @ w^T + b via fp16 MFMA, fused RoPE. K-loop double-
// buffered. XCD swizzle with N FASTEST per XCD chunk: per-XCD working set
// = 2 MB of x (L2-resident) + 6.3 MB of w, vs 16.8 MB x before.
// q fp16 (B,NH,T,D) PRE-SCALED by scl*log2e; k fp16;
// v TRANSPOSED+key-PERMUTED fp16 (pi(nt*16+fr) = fr*4+nt).
// ---------------------------------------------------------------------------
__global__ __launch_bounds__(256) void qkv_gemm_kernel(
    const unsigned short* __restrict__ xf, const unsigned short* __restrict__ wf,
    const float* __restrict__ bias, const float* __restrict__ pe_cos,
    const float* __restrict__ pe_sin, const float* __restrict__ pe_scale,
    unsigned short* __restrict__ qb, unsigned short* __restrict__ kb,
    unsigned short* __restrict__ vtb)
{
    __shared__ __align__(16) unsigned short Ah[2][128 * 32];
    __shared__ __align__(16) unsigned short Bh[2][128 * 32];

    const int tid = threadIdx.x;
    const int w = tid >> 6, lane = tid & 63;
    const int g = lane >> 4, fr = lane & 15;
    const int wr = w >> 1, wc = w & 1;

    const int bid = blockIdx.x;                 // 1536 blocks, XCD swizzle
    const int s = (bid & 7) * 192 + (bid >> 3); // 192 consecutive s per XCD
    const int m0 = (s / 24) * 128;              // m slow: 8 m-rows per XCD
    const int n0 = (s % 24) * 128;              // n fast: all 24 n-cols

    const int c0 = tid, c1 = tid + 256;
    const int r0 = c0 >> 2, r1 = c1 >> 2;
    const int cb0 = ((c0 & 3) * 16) ^ (((r0 >> 1) & 3) << 4);
    const int cb1 = ((c1 & 3) * 16) ^ (((r1 >> 1) & 3) << 4);
    const unsigned short* px0 = xf + (size_t)(m0 + r0) * NC + (cb0 >> 1);
    const unsigned short* px1 = xf + (size_t)(m0 + r1) * NC + (cb1 >> 1);
    const unsigned short* pw0 = wf + (size_t)(n0 + r0) * NC + (cb0 >> 1);
    const unsigned short* pw1 = wf + (size_t)(n0 + r1) * NC + (cb1 >> 1);

#define GSTAGE(buf, k0)                                                         \
    do {                                                                        \
        GLL16(px0 + (k0), (char*)Ah[buf] + c0 * 16);                            \
        GLL16(px1 + (k0), (char*)Ah[buf] + c1 * 16);                            \
        GLL16(pw0 + (k0), (char*)Bh[buf] + c0 * 16);                            \
        GLL16(pw1 + (k0), (char*)Bh[buf] + c1 * 16);                            \
    } while (0)

    f32x4 acc[4][4];
#pragma unroll
    for (int m = 0; m < 4; ++m)
#pragma unroll
        for (int n = 0; n < 4; ++n) acc[m][n] = (f32x4){0.f, 0.f, 0.f, 0.f};

    GSTAGE(0, 0);
    __syncthreads();
    int cur = 0;

    for (int k0 = 0; k0 < NC; k0 += 32) {
        if (k0 + 32 < NC) GSTAGE(cur ^ 1, k0 + 32);

        half8v a_f[4], b_f[4];
#pragma unroll
        for (int m = 0; m < 4; ++m) {
            const int r = wr * 64 + m * 16 + fr;
            const int off = r * 64 + ((g * 16) ^ (((r >> 1) & 3) << 4));
            a_f[m] = *(const half8v*)((const char*)Ah[cur] + off);
        }
#pragma unroll
        for (int n = 0; n < 4; ++n) {
            const int r = wc * 64 + n * 16 + fr;
            const int off = r * 64 + ((g * 16) ^ (((r >> 1) & 3) << 4));
            b_f[n] = *(const half8v*)((const char*)Bh[cur] + off);
        }
#pragma unroll
        for (int m = 0; m < 4; ++m)
#pragma unroll
            for (int n = 0; n < 4; ++n)
                acc[m][n] = __builtin_amdgcn_mfma_f32_16x16x32_f16(a_f[m], b_f[n], acc[m][n], 0, 0, 0);

        __syncthreads();   // drains vmcnt(0): next tile staged; cur reusable
        cur ^= 1;
    }

    // Epilogue: bias + RoPE (+*scale*scl*log2e q, /scale k), scatter.
    const float QSCL = 0.08838834764831845f * LOG2E;  // 1/sqrt(2*D) * log2e
#pragma unroll
    for (int n = 0; n < 4; ++n) {
        const int col = n0 + wc * 64 + n * 16 + fr;
        const int part = col >> 10;             // wave-uniform (16-col span)
        const int hh = (col & 1023) >> 6;
        const int dd = col & 63;
        const float bv = bias[col];
        if (part < 2) {
            unsigned short* outp = (part == 0) ? qb : kb;
#pragma unroll
            for (int m = 0; m < 4; ++m) {
                const int row0 = m0 + wr * 64 + m * 16 + 4 * g;
                const int bb = row0 >> 11;
                const int t0 = row0 & 2047;
#pragma unroll
                for (int j = 0; j < 4; ++j) {
                    const int t = t0 + j;
                    float val = acc[m][n][j] + bv;
                    const float partner = __shfl_xor(val, 1, 64);
                    const int pidx = t * HDIM + dd;
                    const float cc = pe_cos[pidx], ss = pe_sin[pidx], sc = pe_scale[pidx];
                    const float r = (dd & 1) ? (val * cc + partner * ss)
                                             : (val * cc - partner * ss);
                    val = (part == 0) ? (r * sc * QSCL) : (r / sc);
                    outp[(((size_t)bb * NHEADS + hh) * NT + t) * HDIM + dd] = f2h(val);
                }
            }
        } else {
            // v: key-permuted transpose. Thread holds keys {nt=m, fr'=4g+j}
            // across m -> pos (4g+j)*4 + m are 4 consecutive -> ushort4.
            const int rowb = m0 + wr * 64;       // 64-aligned
            const int bb = rowb >> 11;
            const int tb = rowb & 2047;
            unsigned short* vp2 =
                &vtb[(((size_t)bb * NHEADS + hh) * HDIM + dd) * NT + tb];
#pragma unroll
            for (int j = 0; j < 4; ++j) {
                ushort4 sv;
                sv.x = f2h(acc[0][n][j] + bv);
                sv.y = f2h(acc[1][n][j] + bv);
                sv.z = f2h(acc[2][n][j] + bv);
                sv.w = f2h(acc[3][n][j] + bv);
                *(ushort4*)&vp2[(4 * g + j) * 4] = sv;
            }
        }
    }
}

// ---------------------------------------------------------------------------
// Kernel 2: flash attention, fp16 MFMA (round-20 = best measured, 124.5us).
// Mask (fp16, q-quad, log2e-prescaled) enters as the QK^T MFMA C-init.
// kt-loop unrolled x2 with named mask reg buffers; s_setprio(1) around the
// PV MFMA cluster (T5). Unshifted exact softmax (bounded scores).
// ---------------------------------------------------------------------------
__global__ __launch_bounds__(256) void attn_mfma_kernel(
    const unsigned short* __restrict__ qb, const unsigned short* __restrict__ kb,
    const unsigned short* __restrict__ vtb, const unsigned short* __restrict__ m16,
    float* __restrict__ out)
{
    __shared__ __align__(16) unsigned short Ks[2][64 * 64];
    __shared__ __align__(16) unsigned short Vs[2][64 * 64];
    __shared__ __align__(16) unsigned short Ps[4][32 * 64];

    const int tid = threadIdx.x;
    const int w = tid >> 6, lane = tid & 63;
    const int g = lane >> 4, fr = lane & 15;

    const int bid = blockIdx.x;                  // 1024 blocks, XCD swizzle
    const int s = (bid & 7) * 128 + (bid >> 3);
    const int q0 = (s & 15) * 128;
    const int h = (s >> 4) & 15;
    const int b = s >> 8;

    const size_t bh = (size_t)b * NHEADS + h;
    const unsigned short* qp = qb + (bh * NT + q0 + w * 32) * HDIM;
    const unsigned short* kp = kb + bh * NT * HDIM;
    const unsigned short* vtp = vtb + bh * HDIM * NT;
    // q-quad mask base: Qbase = (q0 + w*32) >> 2
    const unsigned short* mp =
        m16 + 4 * (((size_t)b * 512 + ((q0 + w * 32) >> 2)) * 2048);

    const int sc0 = tid, sc1 = tid + 256;
    const int sr0 = sc0 >> 3, scb0 = ((sc0 & 7) * 16) ^ ((sr0 & 7) << 4);
    const int sr1 = sc1 >> 3, scb1 = ((sc1 & 7) * 16) ^ ((sr1 & 7) << 4);

#define STAGE(buf, kt)                                                          \
    do {                                                                        \
        const unsigned short* ktp_ = kp + (kt) * 64 * HDIM;                     \
        GLL16(ktp_ + sr0 * HDIM + (scb0 >> 1), (char*)Ks[buf] + sc0 * 16);      \
        GLL16(vtp + (size_t)sr0 * NT + (kt) * 64 + (scb0 >> 1),                 \
              (char*)Vs[buf] + sc0 * 16);                                       \
        GLL16(ktp_ + sr1 * HDIM + (scb1 >> 1), (char*)Ks[buf] + sc1 * 16);      \
        GLL16(vtp + (size_t)sr1 * NT + (kt) * 64 + (scb1 >> 1),                 \
              (char*)Vs[buf] + sc1 * 16);                                       \
    } while (0)

// dst[m][nt] = {mask(q=4*(Qbase+m*4+g)+j, k=kt*64+nt*16+fr)} j=0..3
#define MLOAD(dst, kt)                                                          \
    do {                                                                        \
        _Pragma("unroll")                                                       \
        for (int m_ = 0; m_ < 2; ++m_) {                                        \
            _Pragma("unroll")                                                   \
            for (int nt_ = 0; nt_ < 4; ++nt_)                                   \
                dst[m_][nt_] = *(const ushort4*)(                               \
                    mp + ((m_ * 4 + g) * 2048 + (kt) * 64 + nt_ * 16 + fr) * 4); \
        }                                                                       \
    } while (0)

    half8v qf[2][2];
#pragma unroll
    for (int m = 0; m < 2; ++m)
#pragma unroll
        for (int kk = 0; kk < 2; ++kk)
            qf[m][kk] = *(const half8v*)(qp + (m * 16 + fr) * HDIM + kk * 32 + g * 8);

    f32x4 acc[2][4];
    float li[2][4];
#pragma unroll
    for (int m = 0; m < 2; ++m)
#pragma unroll
        for (int j = 0; j < 4; ++j) {
            li[m][j] = 0.f;
            acc[m][j] = (f32x4){0.f, 0.f, 0.f, 0.f};
        }

    // compute body for one K/V tile (BUF) with mask regs MV
    auto body = [&](const unsigned short* KsB, const unsigned short* VsB,
                    const ushort4 (&mv)[2][4]) {
        half8v kf[4][2];
#pragma unroll
        for (int nt = 0; nt < 4; ++nt) {
            const int r = nt * 16 + fr;
#pragma unroll
            for (int kk = 0; kk < 2; ++kk) {
                const int off = r * 128 + ((kk * 64 + g * 16) ^ ((r & 7) << 4));
                kf[nt][kk] = *(const half8v*)((const char*)KsB + off);
            }
        }

#pragma unroll
        for (int m = 0; m < 2; ++m) {
            f32x4 Sm[4];
#pragma unroll
            for (int nt = 0; nt < 4; ++nt) {
                const ushort4 mq = mv[m][nt];
                Sm[nt] = (f32x4){h2f(mq.x), h2f(mq.y), h2f(mq.z), h2f(mq.w)};
#pragma unroll
                for (int kk = 0; kk < 2; ++kk)
                    Sm[nt] = __builtin_amdgcn_mfma_f32_16x16x32_f16(qf[m][kk], kf[nt][kk], Sm[nt], 0, 0, 0);
            }
#pragma unroll
            for (int j = 0; j < 4; ++j) {
                const float p0 = exp2fast(Sm[0][j]);
                const float p1 = exp2fast(Sm[1][j]);
                const float p2 = exp2fast(Sm[2][j]);
                const float p3 = exp2fast(Sm[3][j]);
                li[m][j] += (p0 + p1) + (p2 + p3);
                uint2 pw2;
                pw2.x = pack2h(p0, p1);
                pw2.y = pack2h(p2, p3);
                const int prow = m * 16 + 4 * g + j;
                const int off = prow * 128 + ((fr * 8) ^ ((prow & 7) << 4));
                *(uint2*)((char*)Ps[w] + off) = pw2;
            }
        }

        half8v vf[4][2];
#pragma unroll
        for (int dt = 0; dt < 4; ++dt) {
            const int d = dt * 16 + fr;
#pragma unroll
            for (int kk = 0; kk < 2; ++kk) {
                const int off = d * 128 + ((kk * 64 + g * 16) ^ ((d & 7) << 4));
                vf[dt][kk] = *(const half8v*)((const char*)VsB + off);
            }
        }
        __builtin_amdgcn_s_setprio(1);
#pragma unroll
        for (int m = 0; m < 2; ++m) {
            half8v pf[2];
#pragma unroll
            for (int kk = 0; kk < 2; ++kk) {
                const int off = (m * 16 + fr) * 128 + ((kk * 64 + g * 16) ^ ((fr & 7) << 4));
                pf[kk] = *(const half8v*)((const char*)Ps[w] + off);
            }
#pragma unroll
            for (int dt = 0; dt < 4; ++dt)
#pragma unroll
                for (int kk = 0; kk < 2; ++kk)
                    acc[m][dt] = __builtin_amdgcn_mfma_f32_16x16x32_f16(pf[kk], vf[dt][kk], acc[m][dt], 0, 0, 0);
        }
        __builtin_amdgcn_s_setprio(0);
    };

    ushort4 mA[2][4], mB[2][4];
    MLOAD(mA, 0);
    STAGE(0, 0);
    __syncthreads();

    for (int kt = 0; kt < NT / 64; kt += 2) {
        // iter A: compute on buf0/mA, prefetch kt+1 into buf1/mB
        if (kt + 1 < NT / 64) {
            STAGE(1, kt + 1);
            MLOAD(mB, kt + 1);
        }
        body(Ks[0], Vs[0], mA);
        __syncthreads();

        // iter B: compute on buf1/mB, prefetch kt+2 into buf0/mA
        if (kt + 2 < NT / 64) {
            STAGE(0, kt + 2);
            MLOAD(mA, kt + 2);
        }
        body(Ks[1], Vs[1], mB);
        __syncthreads();
    }

#pragma unroll
    for (int m = 0; m < 2; ++m)
#pragma unroll
        for (int j = 0; j < 4; ++j) {
            float lt = li[m][j];
            lt += __shfl_xor(lt, 1, 64);
            lt += __shfl_xor(lt, 2, 64);
            lt += __shfl_xor(lt, 4, 64);
            lt += __shfl_xor(lt, 8, 64);
            const float inv = 1.f / lt;
            const int t = q0 + w * 32 + m * 16 + 4 * g + j;
            float* op = out + (((size_t)b * NT + t) * NHEADS + h) * HDIM;
#pragma unroll
            for (int dt = 0; dt < 4; ++dt) op[dt * 16 + fr] = acc[m][dt][j] * inv;
        }
}

extern "C" void kernel_launch(void* const* d_in, const int* in_sizes, int n_in,
                              void* d_out, int out_size, void* d_ws, size_t ws_size,
                              hipStream_t stream) {
    const float* x        = (const float*)d_in[0];
    const float* pe_cos   = (const float*)d_in[1];
    const float* pe_sin   = (const float*)d_in[2];
    const float* pe_scale = (const float*)d_in[3];
    const float* mask     = (const float*)d_in[4];
    const float* w_qkv    = (const float*)d_in[5];
    const float* b_qkv    = (const float*)d_in[6];
    float* out = (float*)d_out;

    unsigned short* ws = (unsigned short*)d_ws;
    const size_t PER = (size_t)NB * NHEADS * NT * HDIM;   // 8388608
    unsigned short* qbuf = ws;
    unsigned short* kbuf = ws + PER;
    unsigned short* vtbuf = ws + 2 * PER;
    unsigned short* xbuf = ws + 3 * PER;                  // fp16 x (GEMM only)
    unsigned short* wbuf = xbuf + (size_t)NB * NT * NC;   // fp16 w (GEMM only)
    unsigned short* maskbuf = ws + 3 * PER;               // fp16 mask (after GEMM)

    conv_f16_kernel<<<8192, 256, 0, stream>>>(x, xbuf, (NB * NT * NC) / 4);
    conv_f16_kernel<<<3072, 256, 0, stream>>>(w_qkv, wbuf, (3 * NC * NC) / 4);
    qkv_gemm_kernel<<<1536, 256, 0, stream>>>(xbuf, wbuf, b_qkv,
                                              pe_cos, pe_sin, pe_scale,
                                              qbuf, kbuf, vtbuf);
    mask_conv_kernel<<<16384, 256, 0, stream>>>(mask, maskbuf);
    attn_mfma_kernel<<<1024, 256, 0, stream>>>(qbuf, kbuf, vtbuf, maskbuf, out);
}

// Round 22
// 221.009 us; speedup vs baseline: 1.0787x; 1.0396x over previous
//
#include <hip/hip_runtime.h>
#include <math.h>

#define NB 4
#define NT 2048
#define NC 1024
#define NHEADS 16
#define HDIM 64

typedef __attribute__((ext_vector_type(8))) _Float16 half8v;
typedef __attribute__((ext_vector_type(2))) __fp16 fp16x2;
typedef __attribute__((ext_vector_type(4))) float f32x4;

#define LOG2E 1.4426950408889634f

__device__ inline unsigned short f2h(float f) {
    _Float16 h = (_Float16)f;
    return __builtin_bit_cast(unsigned short, h);
}
__device__ inline float h2f(unsigned short u) {
    return (float)__builtin_bit_cast(_Float16, u);
}
__device__ inline float exp2fast(float x) {
#if __has_builtin(__builtin_amdgcn_exp2f)
    return __builtin_amdgcn_exp2f(x);
#else
    return exp2f(x);
#endif
}
__device__ inline unsigned int pack2h(float a, float b) {
    fp16x2 p = __builtin_amdgcn_cvt_pkrtz(a, b);
    return __builtin_bit_cast(unsigned int, p);
}

#define AS1C(p) ((const __attribute__((address_space(1))) unsigned int*)(unsigned long long)(const void*)(p))
#define AS3P(p) ((__attribute__((address_space(3))) unsigned int*)(unsigned int)(unsigned long long)(void*)(p))
#define GLL16(gp, lp) __builtin_amdgcn_global_load_lds(AS1C(gp), AS3P(lp), 16, 0, 0)

// ---------------------------------------------------------------------------
// fused fp32 -> fp16 convert for x (first n4x quads) and w (next n4w quads)
// ---------------------------------------------------------------------------
__global__ __launch_bounds__(256) void convs_f16_kernel(
    const float* __restrict__ xin, unsigned short* __restrict__ xout, int n4x,
    const float* __restrict__ win, unsigned short* __restrict__ wout, int n4w)
{
    const int bid = blockIdx.x;
    const int xblocks = (n4x + 255) / 256;
    if (bid < xblocks) {
        const int i = bid * 256 + threadIdx.x;
        if (i >= n4x) return;
        const float4 f = ((const float4*)xin)[i];
        ushort4 h;
        h.x = f2h(f.x); h.y = f2h(f.y); h.z = f2h(f.z); h.w = f2h(f.w);
        ((ushort4*)xout)[i] = h;
    } else {
        const int i = (bid - xblocks) * 256 + threadIdx.x;
        if (i >= n4w) return;
        const float4 f = ((const float4*)win)[i];
        ushort4 h;
        h.x = f2h(f.x); h.y = f2h(f.y); h.z = f2h(f.z); h.w = f2h(f.w);
        ((ushort4*)wout)[i] = h;
    }
}

// ---------------------------------------------------------------------------
// mask fp32 -> fp16 * log2e, Q-QUAD layout: mask5[b][q>>2][k][q&3]
// (standalone fallback kernel; same body also lives in the fused GEMM)
// ---------------------------------------------------------------------------
__device__ inline void mask_conv_body(const float* __restrict__ in,
                                      unsigned short* __restrict__ out,
                                      size_t o)
{
    const int k = (int)(o & 2047);
    const int Q = (int)((o >> 11) & 511);
    const int b = (int)(o >> 20);
    const float* ip = in + (((size_t)b * 2048 + 4 * Q) * 2048 + k);
    ushort4 v;
    v.x = f2h(ip[0] * LOG2E);
    v.y = f2h(ip[2048] * LOG2E);
    v.z = f2h(ip[4096] * LOG2E);
    v.w = f2h(ip[6144] * LOG2E);
    ((ushort4*)out)[o] = v;
}

__global__ __launch_bounds__(256) void mask_conv_kernel(
    const float* __restrict__ in, unsigned short* __restrict__ out)
{
    mask_conv_body(in, out, (size_t)blockIdx.x * 256 + threadIdx.x);
}

// ---------------------------------------------------------------------------
// Kernel 1: qkv = x @ w^T + b via fp16 MFMA, fused RoPE. K-loop double-
// buffered; n-fast XCD swizzle (round-21). Blocks >= 1536 run the mask
// conversion instead (independent work backfilling CUs as GEMM retires).
// q fp16 (B,NH,T,D) PRE-SCALED by scl*log2e; k fp16;
// v TRANSPOSED+key-PERMUTED fp16 (pi(nt*16+fr) = fr*4+nt).
// ---------------------------------------------------------------------------
__global__ __launch_bounds__(256) void qkv_gemm_kernel(
    const unsigned short* __restrict__ xf, const unsigned short* __restrict__ wf,
    const float* __restrict__ bias, const float* __restrict__ pe_cos,
    const float* __restrict__ pe_sin, const float* __restrict__ pe_scale,
    unsigned short* __restrict__ qb, unsigned short* __restrict__ kb,
    unsigned short* __restrict__ vtb,
    const float* __restrict__ mask_in, unsigned short* __restrict__ mask_out)
{
    __shared__ __align__(16) unsigned short Ah[2][128 * 32];
    __shared__ __align__(16) unsigned short Bh[2][128 * 32];

    const int tid = threadIdx.x;
    if (blockIdx.x >= 1536) {                   // fused mask-conv blocks
        mask_conv_body(mask_in, mask_out,
                       (size_t)(blockIdx.x - 1536) * 256 + tid);
        return;
    }

    const int w = tid >> 6, lane = tid & 63;
    const int g = lane >> 4, fr = lane & 15;
    const int wr = w >> 1, wc = w & 1;

    const int bid = blockIdx.x;                 // 1536 blocks, XCD swizzle
    const int s = (bid & 7) * 192 + (bid >> 3); // 192 consecutive s per XCD
    const int m0 = (s / 24) * 128;              // m slow: 8 m-rows per XCD
    const int n0 = (s % 24) * 128;              // n fast: all 24 n-cols

    const int c0 = tid, c1 = tid + 256;
    const int r0 = c0 >> 2, r1 = c1 >> 2;
    const int cb0 = ((c0 & 3) * 16) ^ (((r0 >> 1) & 3) << 4);
    const int cb1 = ((c1 & 3) * 16) ^ (((r1 >> 1) & 3) << 4);
    const unsigned short* px0 = xf + (size_t)(m0 + r0) * NC + (cb0 >> 1);
    const unsigned short* px1 = xf + (size_t)(m0 + r1) * NC + (cb1 >> 1);
    const unsigned short* pw0 = wf + (size_t)(n0 + r0) * NC + (cb0 >> 1);
    const unsigned short* pw1 = wf + (size_t)(n0 + r1) * NC + (cb1 >> 1);

#define GSTAGE(buf, k0)                                                         \
    do {                                                                        \
        GLL16(px0 + (k0), (char*)Ah[buf] + c0 * 16);                            \
        GLL16(px1 + (k0), (char*)Ah[buf] + c1 * 16);                            \
        GLL16(pw0 + (k0), (char*)Bh[buf] + c0 * 16);                            \
        GLL16(pw1 + (k0), (char*)Bh[buf] + c1 * 16);                            \
    } while (0)

    f32x4 acc[4][4];
#pragma unroll
    for (int m = 0; m < 4; ++m)
#pragma unroll
        for (int n = 0; n < 4; ++n) acc[m][n] = (f32x4){0.f, 0.f, 0.f, 0.f};

    GSTAGE(0, 0);
    __syncthreads();
    int cur = 0;

    for (int k0 = 0; k0 < NC; k0 += 32) {
        if (k0 + 32 < NC) GSTAGE(cur ^ 1, k0 + 32);

        half8v a_f[4], b_f[4];
#pragma unroll
        for (int m = 0; m < 4; ++m) {
            const int r = wr * 64 + m * 16 + fr;
            const int off = r * 64 + ((g * 16) ^ (((r >> 1) & 3) << 4));
            a_f[m] = *(const half8v*)((const char*)Ah[cur] + off);
        }
#pragma unroll
        for (int n = 0; n < 4; ++n) {
            const int r = wc * 64 + n * 16 + fr;
            const int off = r * 64 + ((g * 16) ^ (((r >> 1) & 3) << 4));
            b_f[n] = *(const half8v*)((const char*)Bh[cur] + off);
        }
#pragma unroll
        for (int m = 0; m < 4; ++m)
#pragma unroll
            for (int n = 0; n < 4; ++n)
                acc[m][n] = __builtin_amdgcn_mfma_f32_16x16x32_f16(a_f[m], b_f[n], acc[m][n], 0, 0, 0);

        __syncthreads();   // drains vmcnt(0): next tile staged; cur reusable
        cur ^= 1;
    }

    // Epilogue: bias + RoPE (+*scale*scl*log2e q, /scale k), scatter.
    const float QSCL = 0.08838834764831845f * LOG2E;  // 1/sqrt(2*D) * log2e
#pragma unroll
    for (int n = 0; n < 4; ++n) {
        const int col = n0 + wc * 64 + n * 16 + fr;
        const int part = col >> 10;             // wave-uniform (16-col span)
        const int hh = (col & 1023) >> 6;
        const int dd = col & 63;
        const float bv = bias[col];
        if (part < 2) {
            unsigned short* outp = (part == 0) ? qb : kb;
#pragma unroll
            for (int m = 0; m < 4; ++m) {
                const int row0 = m0 + wr * 64 + m * 16 + 4 * g;
                const int bb = row0 >> 11;
                const int t0 = row0 & 2047;
#pragma unroll
                for (int j = 0; j < 4; ++j) {
                    const int t = t0 + j;
                    float val = acc[m][n][j] + bv;
                    const float partner = __shfl_xor(val, 1, 64);
                    const int pidx = t * HDIM + dd;
                    const float cc = pe_cos[pidx], ss = pe_sin[pidx], sc = pe_scale[pidx];
                    const float r = (dd & 1) ? (val * cc + partner * ss)
                                             : (val * cc - partner * ss);
                    val = (part == 0) ? (r * sc * QSCL) : (r / sc);
                    outp[(((size_t)bb * NHEADS + hh) * NT + t) * HDIM + dd] = f2h(val);
                }
            }
        } else {
            // v: key-permuted transpose. Thread holds keys {nt=m, fr'=4g+j}
            // across m -> pos (4g+j)*4 + m are 4 consecutive -> ushort4.
            const int rowb = m0 + wr * 64;       // 64-aligned
            const int bb = rowb >> 11;
            const int tb = rowb & 2047;
            unsigned short* vp2 =
                &vtb[(((size_t)bb * NHEADS + hh) * HDIM + dd) * NT + tb];
#pragma unroll
            for (int j = 0; j < 4; ++j) {
                ushort4 sv;
                sv.x = f2h(acc[0][n][j] + bv);
                sv.y = f2h(acc[1][n][j] + bv);
                sv.z = f2h(acc[2][n][j] + bv);
                sv.w = f2h(acc[3][n][j] + bv);
                *(ushort4*)&vp2[(4 * g + j) * 4] = sv;
            }
        }
    }
}

// ---------------------------------------------------------------------------
// Kernel 2: flash attention, fp16 MFMA (round-20/21 = best measured).
// Mask (fp16, q-quad, log2e-prescaled) enters as the QK^T MFMA C-init.
// kt-loop unrolled x2 with named mask reg buffers; s_setprio(1) around the
// PV MFMA cluster (T5). Unshifted exact softmax (bounded scores).
// ---------------------------------------------------------------------------
__global__ __launch_bounds__(256) void attn_mfma_kernel(
    const unsigned short* __restrict__ qb, const unsigned short* __restrict__ kb,
    const unsigned short* __restrict__ vtb, const unsigned short* __restrict__ m16,
    float* __restrict__ out)
{
    __shared__ __align__(16) unsigned short Ks[2][64 * 64];
    __shared__ __align__(16) unsigned short Vs[2][64 * 64];
    __shared__ __align__(16) unsigned short Ps[4][32 * 64];

    const int tid = threadIdx.x;
    const int w = tid >> 6, lane = tid & 63;
    const int g = lane >> 4, fr = lane & 15;

    const int bid = blockIdx.x;                  // 1024 blocks, XCD swizzle
    const int s = (bid & 7) * 128 + (bid >> 3);
    const int q0 = (s & 15) * 128;
    const int h = (s >> 4) & 15;
    const int b = s >> 8;

    const size_t bh = (size_t)b * NHEADS + h;
    const unsigned short* qp = qb + (bh * NT + q0 + w * 32) * HDIM;
    const unsigned short* kp = kb + bh * NT * HDIM;
    const unsigned short* vtp = vtb + bh * HDIM * NT;
    // q-quad mask base: Qbase = (q0 + w*32) >> 2
    const unsigned short* mp =
        m16 + 4 * (((size_t)b * 512 + ((q0 + w * 32) >> 2)) * 2048);

    const int sc0 = tid, sc1 = tid + 256;
    const int sr0 = sc0 >> 3, scb0 = ((sc0 & 7) * 16) ^ ((sr0 & 7) << 4);
    const int sr1 = sc1 >> 3, scb1 = ((sc1 & 7) * 16) ^ ((sr1 & 7) << 4);

#define STAGE(buf, kt)                                                          \
    do {                                                                        \
        const unsigned short* ktp_ = kp + (kt) * 64 * HDIM;                     \
        GLL16(ktp_ + sr0 * HDIM + (scb0 >> 1), (char*)Ks[buf] + sc0 * 16);      \
        GLL16(vtp + (size_t)sr0 * NT + (kt) * 64 + (scb0 >> 1),                 \
              (char*)Vs[buf] + sc0 * 16);                                       \
        GLL16(ktp_ + sr1 * HDIM + (scb1 >> 1), (char*)Ks[buf] + sc1 * 16);      \
        GLL16(vtp + (size_t)sr1 * NT + (kt) * 64 + (scb1 >> 1),                 \
              (char*)Vs[buf] + sc1 * 16);                                       \
    } while (0)

// dst[m][nt] = {mask(q=4*(Qbase+m*4+g)+j, k=kt*64+nt*16+fr)} j=0..3
#define MLOAD(dst, kt)                                                          \
    do {                                                                        \
        _Pragma("unroll")                                                       \
        for (int m_ = 0; m_ < 2; ++m_) {                                        \
            _Pragma("unroll")                                                   \
            for (int nt_ = 0; nt_ < 4; ++nt_)                                   \
                dst[m_][nt_] = *(const ushort4*)(                               \
                    mp + ((m_ * 4 + g) * 2048 + (kt) * 64 + nt_ * 16 + fr) * 4); \
        }                                                                       \
    } while (0)

    half8v qf[2][2];
#pragma unroll
    for (int m = 0; m < 2; ++m)
#pragma unroll
        for (int kk = 0; kk < 2; ++kk)
            qf[m][kk] = *(const half8v*)(qp + (m * 16 + fr) * HDIM + kk * 32 + g * 8);

    f32x4 acc[2][4];
    float li[2][4];
#pragma unroll
    for (int m = 0; m < 2; ++m)
#pragma unroll
        for (int j = 0; j < 4; ++j) {
            li[m][j] = 0.f;
            acc[m][j] = (f32x4){0.f, 0.f, 0.f, 0.f};
        }

    // compute body for one K/V tile (BUF) with mask regs MV
    auto body = [&](const unsigned short* KsB, const unsigned short* VsB,
                    const ushort4 (&mv)[2][4]) {
        half8v kf[4][2];
#pragma unroll
        for (int nt = 0; nt < 4; ++nt) {
            const int r = nt * 16 + fr;
#pragma unroll
            for (int kk = 0; kk < 2; ++kk) {
                const int off = r * 128 + ((kk * 64 + g * 16) ^ ((r & 7) << 4));
                kf[nt][kk] = *(const half8v*)((const char*)KsB + off);
            }
        }

#pragma unroll
        for (int m = 0; m < 2; ++m) {
            f32x4 Sm[4];
#pragma unroll
            for (int nt = 0; nt < 4; ++nt) {
                const ushort4 mq = mv[m][nt];
                Sm[nt] = (f32x4){h2f(mq.x), h2f(mq.y), h2f(mq.z), h2f(mq.w)};
#pragma unroll
                for (int kk = 0; kk < 2; ++kk)
                    Sm[nt] = __builtin_amdgcn_mfma_f32_16x16x32_f16(qf[m][kk], kf[nt][kk], Sm[nt], 0, 0, 0);
            }
#pragma unroll
            for (int j = 0; j < 4; ++j) {
                const float p0 = exp2fast(Sm[0][j]);
                const float p1 = exp2fast(Sm[1][j]);
                const float p2 = exp2fast(Sm[2][j]);
                const float p3 = exp2fast(Sm[3][j]);
                li[m][j] += (p0 + p1) + (p2 + p3);
                uint2 pw2;
                pw2.x = pack2h(p0, p1);
                pw2.y = pack2h(p2, p3);
                const int prow = m * 16 + 4 * g + j;
                const int off = prow * 128 + ((fr * 8) ^ ((prow & 7) << 4));
                *(uint2*)((char*)Ps[w] + off) = pw2;
            }
        }

        half8v vf[4][2];
#pragma unroll
        for (int dt = 0; dt < 4; ++dt) {
            const int d = dt * 16 + fr;
#pragma unroll
            for (int kk = 0; kk < 2; ++kk) {
                const int off = d * 128 + ((kk * 64 + g * 16) ^ ((d & 7) << 4));
                vf[dt][kk] = *(const half8v*)((const char*)VsB + off);
            }
        }
        __builtin_amdgcn_s_setprio(1);
#pragma unroll
        for (int m = 0; m < 2; ++m) {
            half8v pf[2];
#pragma unroll
            for (int kk = 0; kk < 2; ++kk) {
                const int off = (m * 16 + fr) * 128 + ((kk * 64 + g * 16) ^ ((fr & 7) << 4));
                pf[kk] = *(const half8v*)((const char*)Ps[w] + off);
            }
#pragma unroll
            for (int dt = 0; dt < 4; ++dt)
#pragma unroll
                for (int kk = 0; kk < 2; ++kk)
                    acc[m][dt] = __builtin_amdgcn_mfma_f32_16x16x32_f16(pf[kk], vf[dt][kk], acc[m][dt], 0, 0, 0);
        }
        __builtin_amdgcn_s_setprio(0);
    };

    ushort4 mA[2][4], mB[2][4];
    MLOAD(mA, 0);
    STAGE(0, 0);
    __syncthreads();

    for (int kt = 0; kt < NT / 64; kt += 2) {
        // iter A: compute on buf0/mA, prefetch kt+1 into buf1/mB
        if (kt + 1 < NT / 64) {
            STAGE(1, kt + 1);
            MLOAD(mB, kt + 1);
        }
        body(Ks[0], Vs[0], mA);
        __syncthreads();

        // iter B: compute on buf1/mB, prefetch kt+2 into buf0/mA
        if (kt + 2 < NT / 64) {
            STAGE(0, kt + 2);
            MLOAD(mA, kt + 2);
        }
        body(Ks[1], Vs[1], mB);
        __syncthreads();
    }

#pragma unroll
    for (int m = 0; m < 2; ++m)
#pragma unroll
        for (int j = 0; j < 4; ++j) {
            float lt = li[m][j];
            lt += __shfl_xor(lt, 1, 64);
            lt += __shfl_xor(lt, 2, 64);
            lt += __shfl_xor(lt, 4, 64);
            lt += __shfl_xor(lt, 8, 64);
            const float inv = 1.f / lt;
            const int t = q0 + w * 32 + m * 16 + 4 * g + j;
            float* op = out + (((size_t)b * NT + t) * NHEADS + h) * HDIM;
#pragma unroll
            for (int dt = 0; dt < 4; ++dt) op[dt * 16 + fr] = acc[m][dt][j] * inv;
        }
}

extern "C" void kernel_launch(void* const* d_in, const int* in_sizes, int n_in,
                              void* d_out, int out_size, void* d_ws, size_t ws_size,
                              hipStream_t stream) {
    const float* x        = (const float*)d_in[0];
    const float* pe_cos   = (const float*)d_in[1];
    const float* pe_sin   = (const float*)d_in[2];
    const float* pe_scale = (const float*)d_in[3];
    const float* mask     = (const float*)d_in[4];
    const float* w_qkv    = (const float*)d_in[5];
    const float* b_qkv    = (const float*)d_in[6];
    float* out = (float*)d_out;

    unsigned short* ws = (unsigned short*)d_ws;
    const size_t PER = (size_t)NB * NHEADS * NT * HDIM;   // 8388608
    const size_t WLEN = (size_t)3 * NC * NC;              // 3145728
    unsigned short* qbuf = ws;
    unsigned short* kbuf = ws + PER;
    unsigned short* vtbuf = ws + 2 * PER;
    unsigned short* xbuf = ws + 3 * PER;                  // fp16 x (GEMM only)
    unsigned short* wbuf = xbuf + PER;                    // fp16 w (GEMM only)

    // fused path needs a mask buffer that does NOT overlap GEMM inputs:
    const size_t fusedNeedBytes = (6 * PER + WLEN) * sizeof(unsigned short);
    const bool fused = ws_size >= fusedNeedBytes;

    convs_f16_kernel<<<8192 + 3072, 256, 0, stream>>>(
        x, xbuf, (NB * NT * NC) / 4, w_qkv, wbuf, (3 * NC * NC) / 4);

    if (fused) {
        unsigned short* maskbuf = wbuf + WLEN;            // separate region
        qkv_gemm_kernel<<<1536 + 16384, 256, 0, stream>>>(
            xbuf, wbuf, b_qkv, pe_cos, pe_sin, pe_scale,
            qbuf, kbuf, vtbuf, mask, maskbuf);
        attn_mfma_kernel<<<1024, 256, 0, stream>>>(qbuf, kbuf, vtbuf, maskbuf, out);
    } else {
        unsigned short* maskbuf = ws + 3 * PER;           // reuse x/w region
        qkv_gemm_kernel<<<1536, 256, 0, stream>>>(
            xbuf, wbuf, b_qkv, pe_cos, pe_sin, pe_scale,
            qbuf, kbuf, vtbuf, mask, maskbuf /*unused: no blocks >=1536*/);
        mask_conv_kernel<<<16384, 256, 0, stream>>>(mask, maskbuf);
        attn_mfma_kernel<<<1024, 256, 0, stream>>>(qbuf, kbuf, vtbuf, maskbuf, out);
    }
}